// Round 1
// baseline (846.207 us; speedup 1.0000x reference)
//
#include <hip/hip_runtime.h>
#include <hip/hip_bf16.h>

// GraphConv x2:
//   h   = relu( seg_sum(x[src]->dst) @ Wr1^T + b1 + x @ Wo1^T )
//   out =       seg_sum(h[src]->dst) @ Wr2^T + b2 + h @ Wo2^T
// Key identity: seg_sum(h[src]) @ W^T == seg_sum((h @ W^T)[src])  -> transform first,
// aggregate after (halves layer-2 gather traffic). Aggregation via in-kernel CSR
// (histogram + scan + fill), gather-sum per node -> no fp32 atomics.

#define BM 128
#define BK 32

// ---------------- CSR build ----------------

__global__ __launch_bounds__(256) void hist_kernel(const int* __restrict__ dst,
                                                   int* __restrict__ deg, int E) {
    int e = blockIdx.x * blockDim.x + threadIdx.x;
    if (e < E) atomicAdd(&deg[dst[e]], 1);
}

__global__ __launch_bounds__(1024) void scan_kernel(const int* __restrict__ deg,
                                                    int* __restrict__ off,
                                                    int* __restrict__ cursor, int N) {
    const int T = 1024;
    int t = threadIdx.x;
    int chunk = (N + T - 1) / T;
    int lo = t * chunk;
    int hi = lo + chunk; if (hi > N) hi = N;
    int s = 0;
    for (int i = lo; i < hi; ++i) s += deg[i];
    __shared__ int sums[1024];
    sums[t] = s;
    __syncthreads();
    for (int d = 1; d < T; d <<= 1) {
        int v = (t >= d) ? sums[t - d] : 0;
        __syncthreads();
        sums[t] += v;
        __syncthreads();
    }
    int excl = (t == 0) ? 0 : sums[t - 1];
    for (int i = lo; i < hi; ++i) {
        off[i] = excl;
        cursor[i] = excl;
        excl += deg[i];
    }
    if (t == T - 1) off[N] = sums[T - 1];
}

__global__ __launch_bounds__(256) void fill_kernel(const int* __restrict__ src,
                                                   const int* __restrict__ dst,
                                                   int* __restrict__ cursor,
                                                   int* __restrict__ csr, int E) {
    int e = blockIdx.x * blockDim.x + threadIdx.x;
    if (e < E) {
        int pos = atomicAdd(&cursor[dst[e]], 1);
        csr[pos] = src[e];
    }
}

// ---------------- GEMM: OUT[g][j] = sum_k X[g][k] * W[j][k] (+ epilogue) ----------------
// X: [Nrows][128] row-major. W: [BN][128] row-major. EPI: 0 none, 1 relu(AGG+bias+acc), 2 AGG+bias+acc.

template <int BN, int EPI>
__global__ __launch_bounds__(256, 4)
void gemm_k(const float* __restrict__ X, const float* __restrict__ W,
            const float* __restrict__ AGG, const float* __restrict__ bias,
            float* __restrict__ OUT, int Nrows) {
    __shared__ float xs[BK][BM + 4];   // transposed x chunk: xs[k][row]
    __shared__ float wsh[BK][BN + 4];  // transposed W chunk: wsh[k][col]

    const int tid = threadIdx.x;
    const int tc = tid & 15;   // col group
    const int tr = tid >> 4;   // row group (0..15)
    const int rowBase = blockIdx.x * BM;
    constexpr int CG = BN / 64;  // 2 for BN=128, 1 for BN=64

    float acc[8][4 * CG];
#pragma unroll
    for (int i = 0; i < 8; ++i)
#pragma unroll
        for (int j = 0; j < 4 * CG; ++j) acc[i][j] = 0.f;

    const int srow = tid >> 3;       // 0..31
    const int skq = (tid & 7) * 4;   // k offset within chunk: 0,4,..,28

    for (int kc = 0; kc < 128; kc += BK) {
        // stage X chunk (transpose into LDS)
#pragma unroll
        for (int i = 0; i < 4; ++i) {
            int r = srow + i * 32;
            int g = rowBase + r;
            g = g < Nrows ? g : Nrows - 1;
            const float4 v = *(const float4*)(X + (size_t)g * 128 + kc + skq);
            xs[skq + 0][r] = v.x;
            xs[skq + 1][r] = v.y;
            xs[skq + 2][r] = v.z;
            xs[skq + 3][r] = v.w;
        }
        // stage W chunk (transpose into LDS)
#pragma unroll
        for (int i = 0; i < BN / 32; ++i) {
            int j = srow + i * 32;
            const float4 v = *(const float4*)(W + (size_t)j * 128 + kc + skq);
            wsh[skq + 0][j] = v.x;
            wsh[skq + 1][j] = v.y;
            wsh[skq + 2][j] = v.z;
            wsh[skq + 3][j] = v.w;
        }
        __syncthreads();
#pragma unroll
        for (int k = 0; k < BK; ++k) {
            const float4 xa = *(const float4*)&xs[k][tr * 8];
            const float4 xb = *(const float4*)&xs[k][tr * 8 + 4];
            float xr[8] = {xa.x, xa.y, xa.z, xa.w, xb.x, xb.y, xb.z, xb.w};
            float wv[4 * CG];
            const float4 wa = *(const float4*)&wsh[k][tc * 4];
            wv[0] = wa.x; wv[1] = wa.y; wv[2] = wa.z; wv[3] = wa.w;
            if (CG == 2) {
                const float4 wb = *(const float4*)&wsh[k][64 + tc * 4];
                wv[4] = wb.x; wv[5] = wb.y; wv[6] = wb.z; wv[7] = wb.w;
            }
#pragma unroll
            for (int i = 0; i < 8; ++i)
#pragma unroll
                for (int j = 0; j < 4 * CG; ++j) acc[i][j] += xr[i] * wv[j];
        }
        __syncthreads();
    }

    // epilogue
#pragma unroll
    for (int i = 0; i < 8; ++i) {
        int g = rowBase + tr * 8 + i;
        if (g >= Nrows) continue;
#pragma unroll
        for (int cg = 0; cg < CG; ++cg) {
            int c = cg * 64 + tc * 4;
            float4 r;
            r.x = acc[i][cg * 4 + 0];
            r.y = acc[i][cg * 4 + 1];
            r.z = acc[i][cg * 4 + 2];
            r.w = acc[i][cg * 4 + 3];
            if (EPI != 0) {
                const float4 a = *(const float4*)(AGG + (size_t)g * BN + c);
                const float4 bb = *(const float4*)(bias + c);
                r.x += a.x + bb.x;
                r.y += a.y + bb.y;
                r.z += a.z + bb.z;
                r.w += a.w + bb.w;
                if (EPI == 1) {
                    r.x = r.x > 0.f ? r.x : 0.f;
                    r.y = r.y > 0.f ? r.y : 0.f;
                    r.z = r.z > 0.f ? r.z : 0.f;
                    r.w = r.w > 0.f ? r.w : 0.f;
                }
            }
            *(float4*)(OUT + (size_t)g * BN + c) = r;
        }
    }
}

// ---------------- CSR gather-aggregate: OUT[n] = sum_{e in in(n)} F[csr[e]] ----------------

template <int D>  // 128: float2/lane, 64: float/lane
__global__ __launch_bounds__(256)
void agg_k(const float* __restrict__ F, const int* __restrict__ csr,
           const int* __restrict__ off, float* __restrict__ OUT, int N) {
    int n = blockIdx.x * 4 + (threadIdx.x >> 6);
    if (n >= N) return;
    int lane = threadIdx.x & 63;
    int b = off[n], e = off[n + 1];
    if (D == 128) {
        const float2* Fp = (const float2*)F;
        float2 acc; acc.x = 0.f; acc.y = 0.f;
        int i = b;
        for (; i + 4 <= e; i += 4) {
            int s0 = csr[i], s1 = csr[i + 1], s2 = csr[i + 2], s3 = csr[i + 3];
            float2 v0 = Fp[(size_t)s0 * 64 + lane];
            float2 v1 = Fp[(size_t)s1 * 64 + lane];
            float2 v2 = Fp[(size_t)s2 * 64 + lane];
            float2 v3 = Fp[(size_t)s3 * 64 + lane];
            acc.x += (v0.x + v1.x) + (v2.x + v3.x);
            acc.y += (v0.y + v1.y) + (v2.y + v3.y);
        }
        for (; i < e; ++i) {
            int s = csr[i];
            float2 v = Fp[(size_t)s * 64 + lane];
            acc.x += v.x; acc.y += v.y;
        }
        ((float2*)OUT)[(size_t)n * 64 + lane] = acc;
    } else {
        float acc = 0.f;
        int i = b;
        for (; i + 4 <= e; i += 4) {
            int s0 = csr[i], s1 = csr[i + 1], s2 = csr[i + 2], s3 = csr[i + 3];
            float v0 = F[(size_t)s0 * 64 + lane];
            float v1 = F[(size_t)s1 * 64 + lane];
            float v2 = F[(size_t)s2 * 64 + lane];
            float v3 = F[(size_t)s3 * 64 + lane];
            acc += (v0 + v1) + (v2 + v3);
        }
        for (; i < e; ++i) acc += F[(size_t)csr[i] * 64 + lane];
        OUT[(size_t)n * 64 + lane] = acc;
    }
}

extern "C" void kernel_launch(void* const* d_in, const int* in_sizes, int n_in,
                              void* d_out, int out_size, void* d_ws, size_t ws_size,
                              hipStream_t stream) {
    const float* x   = (const float*)d_in[0];
    const int*   ei  = (const int*)d_in[1];
    const float* Wr1 = (const float*)d_in[2];
    const float* br1 = (const float*)d_in[3];
    const float* Wo1 = (const float*)d_in[4];
    const float* Wr2 = (const float*)d_in[5];
    const float* br2 = (const float*)d_in[6];
    const float* Wo2 = (const float*)d_in[7];
    float* out = (float*)d_out;

    const int N = in_sizes[0] / 128;  // 100000
    const int E = in_sizes[1] / 2;    // 1600000

    const int* srcv = ei;
    const int* dstv = ei + E;

    // workspace layout
    float* q1   = (float*)d_ws;                   // N*128   (later reused as h)
    float* agg1 = q1 + (size_t)N * 128;           // N*128   (later reused as p2)
    float* agg2 = agg1 + (size_t)N * 128;         // N*64
    int*   deg  = (int*)(agg2 + (size_t)N * 64);  // N
    int*   off  = deg + N;                        // N+1
    int*   cur  = off + N + 1;                    // N
    int*   csr  = cur + N;                        // E

    const int gemmBlocks = (N + BM - 1) / BM;
    const int aggBlocks = (N + 3) / 4;
    const int edgeBlocks = (E + 255) / 256;

    // CSR build
    hipMemsetAsync(deg, 0, (size_t)N * sizeof(int), stream);
    hist_kernel<<<edgeBlocks, 256, 0, stream>>>(dstv, deg, E);
    scan_kernel<<<1, 1024, 0, stream>>>(deg, off, cur, N);
    fill_kernel<<<edgeBlocks, 256, 0, stream>>>(srcv, dstv, cur, csr, E);

    // layer 1: q1 = x @ Wr1^T ; agg1 = seg_sum(q1) ; h = relu(agg1 + b1 + x @ Wo1^T)
    gemm_k<128, 0><<<gemmBlocks, 256, 0, stream>>>(x, Wr1, nullptr, nullptr, q1, N);
    agg_k<128><<<aggBlocks, 256, 0, stream>>>(q1, csr, off, agg1, N);
    gemm_k<128, 1><<<gemmBlocks, 256, 0, stream>>>(x, Wo1, agg1, br1, q1 /*h*/, N);

    // layer 2: p2 = h @ Wr2^T ; agg2 = seg_sum(p2) ; out = agg2 + b2 + h @ Wo2^T
    gemm_k<64, 0><<<gemmBlocks, 256, 0, stream>>>(q1 /*h*/, Wr2, nullptr, nullptr, agg1 /*p2*/, N);
    agg_k<64><<<aggBlocks, 256, 0, stream>>>(agg1 /*p2*/, csr, off, agg2, N);
    gemm_k<64, 2><<<gemmBlocks, 256, 0, stream>>>(q1 /*h*/, Wo2, agg2, br2, out, N);
}

// Round 3
// 636.674 us; speedup vs baseline: 1.3291x; 1.3291x over previous
//
#include <hip/hip_runtime.h>
#include <hip/hip_bf16.h>

// GraphConv x2:
//   h   = relu( seg_sum(x[src]->dst) @ Wr1^T + b1 + x @ Wo1^T )
//   out =       seg_sum(h[src]->dst) @ Wr2^T + b2 + h @ Wo2^T
// Key identity: seg_sum(h[src]) @ W^T == seg_sum((h @ W^T)[src])  -> transform first,
// aggregate after. Aggregation via in-kernel CSR (histogram + 3-kernel decoupled
// scan + fill), gather-sum per node -> no fp32 atomics.
// R2: replaced 230us single-block scan with parallel 3-kernel scan (~12us).

#define BM 128
#define BK 32

// ---------------- CSR build ----------------

__global__ __launch_bounds__(256) void hist_kernel(const int* __restrict__ dst,
                                                   int* __restrict__ deg, int E) {
    int e = blockIdx.x * blockDim.x + threadIdx.x;
    if (e < E) atomicAdd(&deg[dst[e]], 1);
}

// phase 1: per-block (1024-elem chunk) degree sums
__global__ __launch_bounds__(256) void scan1_kernel(const int* __restrict__ deg,
                                                    int* __restrict__ bsum, int N) {
    int t = threadIdx.x;
    int base = blockIdx.x * 1024 + t * 4;
    int s = 0;
    if (base + 3 < N) {
        int4 v = *(const int4*)(deg + base);
        s = v.x + v.y + v.z + v.w;
    } else {
#pragma unroll
        for (int i = 0; i < 4; ++i)
            if (base + i < N) s += deg[base + i];
    }
#pragma unroll
    for (int d = 32; d > 0; d >>= 1) s += __shfl_down(s, d);
    __shared__ int wsum[4];
    int lane = t & 63, w = t >> 6;
    if (lane == 0) wsum[w] = s;
    __syncthreads();
    if (t == 0) bsum[blockIdx.x] = wsum[0] + wsum[1] + wsum[2] + wsum[3];
}

// phase 2: scan block sums (B <= 256), write exclusive block offsets + off[N]
__global__ __launch_bounds__(256) void scan2_kernel(const int* __restrict__ bsum,
                                                    int* __restrict__ boff,
                                                    int* __restrict__ offN, int B) {
    __shared__ int s[256];
    int t = threadIdx.x;
    int v = (t < B) ? bsum[t] : 0;
    s[t] = v;
    __syncthreads();
    for (int d = 1; d < 256; d <<= 1) {
        int u = (t >= d) ? s[t - d] : 0;
        __syncthreads();
        s[t] += u;
        __syncthreads();
    }
    if (t < B) boff[t] = s[t] - v;   // exclusive
    if (t == B - 1) *offN = s[t];    // total
}

// phase 3: per-block local exclusive scan + block offset -> off, cursor
__global__ __launch_bounds__(256) void scan3_kernel(const int* __restrict__ deg,
                                                    const int* __restrict__ boff,
                                                    int* __restrict__ off,
                                                    int* __restrict__ cursor, int N) {
    int t = threadIdx.x;
    int base = blockIdx.x * 1024 + t * 4;
    int d0 = 0, d1 = 0, d2 = 0, d3 = 0;
    if (base + 3 < N) {
        int4 v = *(const int4*)(deg + base);
        d0 = v.x; d1 = v.y; d2 = v.z; d3 = v.w;
    } else {
        if (base + 0 < N) d0 = deg[base + 0];
        if (base + 1 < N) d1 = deg[base + 1];
        if (base + 2 < N) d2 = deg[base + 2];
    }
    int s = d0 + d1 + d2 + d3;
    int lane = t & 63, w = t >> 6;
    int incl = s;
#pragma unroll
    for (int d = 1; d < 64; d <<= 1) {
        int u = __shfl_up(incl, d);
        if (lane >= d) incl += u;
    }
    __shared__ int wsum[4];
    if (lane == 63) wsum[w] = incl;
    __syncthreads();
    int wpre = 0;
#pragma unroll
    for (int i = 0; i < 3; ++i)
        if (i < w) wpre += wsum[i];
    int excl = incl - s + wpre + boff[blockIdx.x];
    int e0 = excl, e1 = e0 + d0, e2 = e1 + d1, e3 = e2 + d2;
    if (base + 3 < N) {
        *(int4*)(off + base) = make_int4(e0, e1, e2, e3);
        *(int4*)(cursor + base) = make_int4(e0, e1, e2, e3);
    } else {
        if (base + 0 < N) { off[base + 0] = e0; cursor[base + 0] = e0; }
        if (base + 1 < N) { off[base + 1] = e1; cursor[base + 1] = e1; }
        if (base + 2 < N) { off[base + 2] = e2; cursor[base + 2] = e2; }
    }
}

__global__ __launch_bounds__(256) void fill_kernel(const int* __restrict__ src,
                                                   const int* __restrict__ dst,
                                                   int* __restrict__ cursor,
                                                   int* __restrict__ csr, int E) {
    int e = blockIdx.x * blockDim.x + threadIdx.x;
    if (e < E) {
        int pos = atomicAdd(&cursor[dst[e]], 1);
        csr[pos] = src[e];
    }
}

// ---------------- GEMM: OUT[g][j] = sum_k X[g][k] * W[j][k] (+ epilogue) ----------------
// X: [Nrows][128] row-major. W: [BN][128] row-major. EPI: 0 none, 1 relu(AGG+bias+acc), 2 AGG+bias+acc.

template <int BN, int EPI>
__global__ __launch_bounds__(256, 4)
void gemm_k(const float* __restrict__ X, const float* __restrict__ W,
            const float* __restrict__ AGG, const float* __restrict__ bias,
            float* __restrict__ OUT, int Nrows) {
    __shared__ float xs[BK][BM + 4];   // transposed x chunk: xs[k][row]
    __shared__ float wsh[BK][BN + 4];  // transposed W chunk: wsh[k][col]

    const int tid = threadIdx.x;
    const int tc = tid & 15;   // col group
    const int tr = tid >> 4;   // row group (0..15)
    const int rowBase = blockIdx.x * BM;
    constexpr int CG = BN / 64;  // 2 for BN=128, 1 for BN=64

    float acc[8][4 * CG];
#pragma unroll
    for (int i = 0; i < 8; ++i)
#pragma unroll
        for (int j = 0; j < 4 * CG; ++j) acc[i][j] = 0.f;

    const int srow = tid >> 3;       // 0..31
    const int skq = (tid & 7) * 4;   // k offset within chunk: 0,4,..,28

    for (int kc = 0; kc < 128; kc += BK) {
        // stage X chunk (transpose into LDS)
#pragma unroll
        for (int i = 0; i < 4; ++i) {
            int r = srow + i * 32;
            int g = rowBase + r;
            g = g < Nrows ? g : Nrows - 1;
            const float4 v = *(const float4*)(X + (size_t)g * 128 + kc + skq);
            xs[skq + 0][r] = v.x;
            xs[skq + 1][r] = v.y;
            xs[skq + 2][r] = v.z;
            xs[skq + 3][r] = v.w;
        }
        // stage W chunk (transpose into LDS)
#pragma unroll
        for (int i = 0; i < BN / 32; ++i) {
            int j = srow + i * 32;
            const float4 v = *(const float4*)(W + (size_t)j * 128 + kc + skq);
            wsh[skq + 0][j] = v.x;
            wsh[skq + 1][j] = v.y;
            wsh[skq + 2][j] = v.z;
            wsh[skq + 3][j] = v.w;
        }
        __syncthreads();
#pragma unroll
        for (int k = 0; k < BK; ++k) {
            const float4 xa = *(const float4*)&xs[k][tr * 8];
            const float4 xb = *(const float4*)&xs[k][tr * 8 + 4];
            float xr[8] = {xa.x, xa.y, xa.z, xa.w, xb.x, xb.y, xb.z, xb.w};
            float wv[4 * CG];
            const float4 wa = *(const float4*)&wsh[k][tc * 4];
            wv[0] = wa.x; wv[1] = wa.y; wv[2] = wa.z; wv[3] = wa.w;
            if (CG == 2) {
                const float4 wb = *(const float4*)&wsh[k][64 + tc * 4];
                wv[4] = wb.x; wv[5] = wb.y; wv[6] = wb.z; wv[7] = wb.w;
            }
#pragma unroll
            for (int i = 0; i < 8; ++i)
#pragma unroll
                for (int j = 0; j < 4 * CG; ++j) acc[i][j] += xr[i] * wv[j];
        }
        __syncthreads();
    }

    // epilogue
#pragma unroll
    for (int i = 0; i < 8; ++i) {
        int g = rowBase + tr * 8 + i;
        if (g >= Nrows) continue;
#pragma unroll
        for (int cg = 0; cg < CG; ++cg) {
            int c = cg * 64 + tc * 4;
            float4 r;
            r.x = acc[i][cg * 4 + 0];
            r.y = acc[i][cg * 4 + 1];
            r.z = acc[i][cg * 4 + 2];
            r.w = acc[i][cg * 4 + 3];
            if (EPI != 0) {
                const float4 a = *(const float4*)(AGG + (size_t)g * BN + c);
                const float4 bb = *(const float4*)(bias + c);
                r.x += a.x + bb.x;
                r.y += a.y + bb.y;
                r.z += a.z + bb.z;
                r.w += a.w + bb.w;
                if (EPI == 1) {
                    r.x = r.x > 0.f ? r.x : 0.f;
                    r.y = r.y > 0.f ? r.y : 0.f;
                    r.z = r.z > 0.f ? r.z : 0.f;
                    r.w = r.w > 0.f ? r.w : 0.f;
                }
            }
            *(float4*)(OUT + (size_t)g * BN + c) = r;
        }
    }
}

// ---------------- CSR gather-aggregate: OUT[n] = sum_{e in in(n)} F[csr[e]] ----------------

template <int D>  // 128: float2/lane, 64: float/lane
__global__ __launch_bounds__(256)
void agg_k(const float* __restrict__ F, const int* __restrict__ csr,
           const int* __restrict__ off, float* __restrict__ OUT, int N) {
    int n = blockIdx.x * 4 + (threadIdx.x >> 6);
    if (n >= N) return;
    int lane = threadIdx.x & 63;
    int b = off[n], e = off[n + 1];
    if (D == 128) {
        const float2* Fp = (const float2*)F;
        float2 acc; acc.x = 0.f; acc.y = 0.f;
        int i = b;
        for (; i + 4 <= e; i += 4) {
            int s0 = csr[i], s1 = csr[i + 1], s2 = csr[i + 2], s3 = csr[i + 3];
            float2 v0 = Fp[(size_t)s0 * 64 + lane];
            float2 v1 = Fp[(size_t)s1 * 64 + lane];
            float2 v2 = Fp[(size_t)s2 * 64 + lane];
            float2 v3 = Fp[(size_t)s3 * 64 + lane];
            acc.x += (v0.x + v1.x) + (v2.x + v3.x);
            acc.y += (v0.y + v1.y) + (v2.y + v3.y);
        }
        for (; i < e; ++i) {
            int s = csr[i];
            float2 v = Fp[(size_t)s * 64 + lane];
            acc.x += v.x; acc.y += v.y;
        }
        ((float2*)OUT)[(size_t)n * 64 + lane] = acc;
    } else {
        float acc = 0.f;
        int i = b;
        for (; i + 4 <= e; i += 4) {
            int s0 = csr[i], s1 = csr[i + 1], s2 = csr[i + 2], s3 = csr[i + 3];
            float v0 = F[(size_t)s0 * 64 + lane];
            float v1 = F[(size_t)s1 * 64 + lane];
            float v2 = F[(size_t)s2 * 64 + lane];
            float v3 = F[(size_t)s3 * 64 + lane];
            acc += (v0 + v1) + (v2 + v3);
        }
        for (; i < e; ++i) acc += F[(size_t)csr[i] * 64 + lane];
        OUT[(size_t)n * 64 + lane] = acc;
    }
}

extern "C" void kernel_launch(void* const* d_in, const int* in_sizes, int n_in,
                              void* d_out, int out_size, void* d_ws, size_t ws_size,
                              hipStream_t stream) {
    const float* x   = (const float*)d_in[0];
    const int*   ei  = (const int*)d_in[1];
    const float* Wr1 = (const float*)d_in[2];
    const float* br1 = (const float*)d_in[3];
    const float* Wo1 = (const float*)d_in[4];
    const float* Wr2 = (const float*)d_in[5];
    const float* br2 = (const float*)d_in[6];
    const float* Wo2 = (const float*)d_in[7];
    float* out = (float*)d_out;

    const int N = in_sizes[0] / 128;  // 100000
    const int E = in_sizes[1] / 2;    // 1600000

    const int* srcv = ei;
    const int* dstv = ei + E;

    // workspace layout (keep deg/off/cursor 16B-aligned for int4 access)
    float* q1   = (float*)d_ws;                   // N*128   (later reused as h)
    float* agg1 = q1 + (size_t)N * 128;           // N*128   (later reused as p2)
    float* agg2 = agg1 + (size_t)N * 128;         // N*64
    int*   deg  = (int*)(agg2 + (size_t)N * 64);  // N        (N%4==0 -> aligned)
    int*   off  = deg + N;                        // N+1 (padded to N+8)
    int*   cur  = off + N + 8;                    // N
    int*   csr  = cur + N;                        // E
    int*   bsum = csr + E;                        // B
    int*   boff = bsum + 256;                     // B

    const int gemmBlocks = (N + BM - 1) / BM;
    const int aggBlocks = (N + 3) / 4;
    const int edgeBlocks = (E + 255) / 256;
    const int B = (N + 1023) / 1024;  // scan blocks (must be <= 256)

    // CSR build
    hipMemsetAsync(deg, 0, (size_t)N * sizeof(int), stream);
    hist_kernel<<<edgeBlocks, 256, 0, stream>>>(dstv, deg, E);
    scan1_kernel<<<B, 256, 0, stream>>>(deg, bsum, N);
    scan2_kernel<<<1, 256, 0, stream>>>(bsum, boff, off + N, B);
    scan3_kernel<<<B, 256, 0, stream>>>(deg, boff, off, cur, N);
    fill_kernel<<<edgeBlocks, 256, 0, stream>>>(srcv, dstv, cur, csr, E);

    // layer 1: q1 = x @ Wr1^T ; agg1 = seg_sum(q1) ; h = relu(agg1 + b1 + x @ Wo1^T)
    gemm_k<128, 0><<<gemmBlocks, 256, 0, stream>>>(x, Wr1, nullptr, nullptr, q1, N);
    agg_k<128><<<aggBlocks, 256, 0, stream>>>(q1, csr, off, agg1, N);
    gemm_k<128, 1><<<gemmBlocks, 256, 0, stream>>>(x, Wo1, agg1, br1, q1 /*h*/, N);

    // layer 2: p2 = h @ Wr2^T ; agg2 = seg_sum(p2) ; out = agg2 + b2 + h @ Wo2^T
    gemm_k<64, 0><<<gemmBlocks, 256, 0, stream>>>(q1 /*h*/, Wr2, nullptr, nullptr, agg1 /*p2*/, N);
    agg_k<64><<<aggBlocks, 256, 0, stream>>>(agg1 /*p2*/, csr, off, agg2, N);
    gemm_k<64, 2><<<gemmBlocks, 256, 0, stream>>>(q1 /*h*/, Wo2, agg2, br2, out, N);
}

// Round 5
// 590.096 us; speedup vs baseline: 1.4340x; 1.0789x over previous
//
#include <hip/hip_runtime.h>
#include <hip/hip_bf16.h>

// GraphConv x2:
//   h   = relu( seg_sum(x[src]->dst) @ Wr1^T + b1 + x @ Wo1^T )
//   out =       seg_sum(h[src]->dst) @ Wr2^T + b2 + h @ Wo2^T
// Key identity: seg_sum(h[src]) @ W^T == seg_sum((h @ W^T)[src])  -> transform first,
// aggregate after. Aggregation via in-kernel CSR (histogram + 3-kernel decoupled
// scan + fill), gather-sum per node -> no fp32 atomics.
// R2: replaced 230us single-block scan with parallel 3-kernel scan.
// R4: dst-range-partitioned fill (8 disjoint ranges -> per-XCD L2-resident scatter):
//     kills the 16x write-allocate amplification (105MB -> ~6.4MB writes).

#define BM 128
#define BK 32
#define NPASS 8

// ---------------- CSR build ----------------

__global__ __launch_bounds__(256) void hist_kernel(const int* __restrict__ dst,
                                                   int* __restrict__ deg, int E) {
    int e = blockIdx.x * blockDim.x + threadIdx.x;
    if (e < E) atomicAdd(&deg[dst[e]], 1);
}

// phase 1: per-block (1024-elem chunk) degree sums
__global__ __launch_bounds__(256) void scan1_kernel(const int* __restrict__ deg,
                                                    int* __restrict__ bsum, int N) {
    int t = threadIdx.x;
    int base = blockIdx.x * 1024 + t * 4;
    int s = 0;
    if (base + 3 < N) {
        int4 v = *(const int4*)(deg + base);
        s = v.x + v.y + v.z + v.w;
    } else {
#pragma unroll
        for (int i = 0; i < 4; ++i)
            if (base + i < N) s += deg[base + i];
    }
#pragma unroll
    for (int d = 32; d > 0; d >>= 1) s += __shfl_down(s, d);
    __shared__ int wsum[4];
    int lane = t & 63, w = t >> 6;
    if (lane == 0) wsum[w] = s;
    __syncthreads();
    if (t == 0) bsum[blockIdx.x] = wsum[0] + wsum[1] + wsum[2] + wsum[3];
}

// phase 2: scan block sums (B <= 256), write exclusive block offsets + off[N]
__global__ __launch_bounds__(256) void scan2_kernel(const int* __restrict__ bsum,
                                                    int* __restrict__ boff,
                                                    int* __restrict__ offN, int B) {
    __shared__ int s[256];
    int t = threadIdx.x;
    int v = (t < B) ? bsum[t] : 0;
    s[t] = v;
    __syncthreads();
    for (int d = 1; d < 256; d <<= 1) {
        int u = (t >= d) ? s[t - d] : 0;
        __syncthreads();
        s[t] += u;
        __syncthreads();
    }
    if (t < B) boff[t] = s[t] - v;   // exclusive
    if (t == B - 1) *offN = s[t];    // total
}

// phase 3: per-block local exclusive scan + block offset -> off, cursor
__global__ __launch_bounds__(256) void scan3_kernel(const int* __restrict__ deg,
                                                    const int* __restrict__ boff,
                                                    int* __restrict__ off,
                                                    int* __restrict__ cursor, int N) {
    int t = threadIdx.x;
    int base = blockIdx.x * 1024 + t * 4;
    int d0 = 0, d1 = 0, d2 = 0, d3 = 0;
    if (base + 3 < N) {
        int4 v = *(const int4*)(deg + base);
        d0 = v.x; d1 = v.y; d2 = v.z; d3 = v.w;
    } else {
        if (base + 0 < N) d0 = deg[base + 0];
        if (base + 1 < N) d1 = deg[base + 1];
        if (base + 2 < N) d2 = deg[base + 2];
    }
    int s = d0 + d1 + d2 + d3;
    int lane = t & 63, w = t >> 6;
    int incl = s;
#pragma unroll
    for (int d = 1; d < 64; d <<= 1) {
        int u = __shfl_up(incl, d);
        if (lane >= d) incl += u;
    }
    __shared__ int wsum[4];
    if (lane == 63) wsum[w] = incl;
    __syncthreads();
    int wpre = 0;
#pragma unroll
    for (int i = 0; i < 3; ++i)
        if (i < w) wpre += wsum[i];
    int excl = incl - s + wpre + boff[blockIdx.x];
    int e0 = excl, e1 = e0 + d0, e2 = e1 + d1, e3 = e2 + d2;
    if (base + 3 < N) {
        *(int4*)(off + base) = make_int4(e0, e1, e2, e3);
        *(int4*)(cursor + base) = make_int4(e0, e1, e2, e3);
    } else {
        if (base + 0 < N) { off[base + 0] = e0; cursor[base + 0] = e0; }
        if (base + 1 < N) { off[base + 1] = e1; cursor[base + 1] = e1; }
        if (base + 2 < N) { off[base + 2] = e2; cursor[base + 2] = e2; }
    }
}

// R4: dst-range-partitioned fill. pass = blockIdx.x & 7 selects a disjoint dst
// range; with round-robin block->XCD placement each XCD's scatter targets stay
// in its own L2 (csr slice 0.8MB + cursor slice 50KB), so csr lines fill fully
// before one write-back. Edge list re-reads are L3-served.
__global__ __launch_bounds__(256) void fill_kernel(const int* __restrict__ src,
                                                   const int* __restrict__ dst,
                                                   int* __restrict__ cursor,
                                                   int* __restrict__ csr, int E, int N) {
    const int pass = blockIdx.x & (NPASS - 1);
    const int chunk = blockIdx.x >> 3;
    const int rangeSize = (N + NPASS - 1) / NPASS;
    const int lo = pass * rangeSize;
    const int hi = (lo + rangeSize < N) ? lo + rangeSize : N;
    const int base = chunk * 1024 + threadIdx.x * 4;
    if (base + 3 < E) {
        const int4 s4 = *(const int4*)(src + base);
        const int4 d4 = *(const int4*)(dst + base);
        if (d4.x >= lo && d4.x < hi) csr[atomicAdd(&cursor[d4.x], 1)] = s4.x;
        if (d4.y >= lo && d4.y < hi) csr[atomicAdd(&cursor[d4.y], 1)] = s4.y;
        if (d4.z >= lo && d4.z < hi) csr[atomicAdd(&cursor[d4.z], 1)] = s4.z;
        if (d4.w >= lo && d4.w < hi) csr[atomicAdd(&cursor[d4.w], 1)] = s4.w;
    } else {
        for (int i = 0; i < 4; ++i) {
            int e = base + i;
            if (e < E) {
                int d = dst[e];
                if (d >= lo && d < hi) csr[atomicAdd(&cursor[d], 1)] = src[e];
            }
        }
    }
}

// ---------------- GEMM: OUT[g][j] = sum_k X[g][k] * W[j][k] (+ epilogue) ----------------
// X: [Nrows][128] row-major. W: [BN][128] row-major. EPI: 0 none, 1 relu(AGG+bias+acc), 2 AGG+bias+acc.

template <int BN, int EPI>
__global__ __launch_bounds__(256, 4)
void gemm_k(const float* __restrict__ X, const float* __restrict__ W,
            const float* __restrict__ AGG, const float* __restrict__ bias,
            float* __restrict__ OUT, int Nrows) {
    __shared__ float xs[BK][BM + 4];   // transposed x chunk: xs[k][row]
    __shared__ float wsh[BK][BN + 4];  // transposed W chunk: wsh[k][col]

    const int tid = threadIdx.x;
    const int tc = tid & 15;   // col group
    const int tr = tid >> 4;   // row group (0..15)
    const int rowBase = blockIdx.x * BM;
    constexpr int CG = BN / 64;  // 2 for BN=128, 1 for BN=64

    float acc[8][4 * CG];
#pragma unroll
    for (int i = 0; i < 8; ++i)
#pragma unroll
        for (int j = 0; j < 4 * CG; ++j) acc[i][j] = 0.f;

    const int srow = tid >> 3;       // 0..31
    const int skq = (tid & 7) * 4;   // k offset within chunk: 0,4,..,28

    for (int kc = 0; kc < 128; kc += BK) {
        // stage X chunk (transpose into LDS)
#pragma unroll
        for (int i = 0; i < 4; ++i) {
            int r = srow + i * 32;
            int g = rowBase + r;
            g = g < Nrows ? g : Nrows - 1;
            const float4 v = *(const float4*)(X + (size_t)g * 128 + kc + skq);
            xs[skq + 0][r] = v.x;
            xs[skq + 1][r] = v.y;
            xs[skq + 2][r] = v.z;
            xs[skq + 3][r] = v.w;
        }
        // stage W chunk (transpose into LDS)
#pragma unroll
        for (int i = 0; i < BN / 32; ++i) {
            int j = srow + i * 32;
            const float4 v = *(const float4*)(W + (size_t)j * 128 + kc + skq);
            wsh[skq + 0][j] = v.x;
            wsh[skq + 1][j] = v.y;
            wsh[skq + 2][j] = v.z;
            wsh[skq + 3][j] = v.w;
        }
        __syncthreads();
#pragma unroll
        for (int k = 0; k < BK; ++k) {
            const float4 xa = *(const float4*)&xs[k][tr * 8];
            const float4 xb = *(const float4*)&xs[k][tr * 8 + 4];
            float xr[8] = {xa.x, xa.y, xa.z, xa.w, xb.x, xb.y, xb.z, xb.w};
            float wv[4 * CG];
            const float4 wa = *(const float4*)&wsh[k][tc * 4];
            wv[0] = wa.x; wv[1] = wa.y; wv[2] = wa.z; wv[3] = wa.w;
            if (CG == 2) {
                const float4 wb = *(const float4*)&wsh[k][64 + tc * 4];
                wv[4] = wb.x; wv[5] = wb.y; wv[6] = wb.z; wv[7] = wb.w;
            }
#pragma unroll
            for (int i = 0; i < 8; ++i)
#pragma unroll
                for (int j = 0; j < 4 * CG; ++j) acc[i][j] += xr[i] * wv[j];
        }
        __syncthreads();
    }

    // epilogue
#pragma unroll
    for (int i = 0; i < 8; ++i) {
        int g = rowBase + tr * 8 + i;
        if (g >= Nrows) continue;
#pragma unroll
        for (int cg = 0; cg < CG; ++cg) {
            int c = cg * 64 + tc * 4;
            float4 r;
            r.x = acc[i][cg * 4 + 0];
            r.y = acc[i][cg * 4 + 1];
            r.z = acc[i][cg * 4 + 2];
            r.w = acc[i][cg * 4 + 3];
            if (EPI != 0) {
                const float4 a = *(const float4*)(AGG + (size_t)g * BN + c);
                const float4 bb = *(const float4*)(bias + c);
                r.x += a.x + bb.x;
                r.y += a.y + bb.y;
                r.z += a.z + bb.z;
                r.w += a.w + bb.w;
                if (EPI == 1) {
                    r.x = r.x > 0.f ? r.x : 0.f;
                    r.y = r.y > 0.f ? r.y : 0.f;
                    r.z = r.z > 0.f ? r.z : 0.f;
                    r.w = r.w > 0.f ? r.w : 0.f;
                }
            }
            *(float4*)(OUT + (size_t)g * BN + c) = r;
        }
    }
}

// ---------------- CSR gather-aggregate: OUT[n] = sum_{e in in(n)} F[csr[e]] ----------------

template <int D>  // 128: float2/lane, 64: float/lane
__global__ __launch_bounds__(256)
void agg_k(const float* __restrict__ F, const int* __restrict__ csr,
           const int* __restrict__ off, float* __restrict__ OUT, int N) {
    int n = blockIdx.x * 4 + (threadIdx.x >> 6);
    if (n >= N) return;
    int lane = threadIdx.x & 63;
    int b = off[n], e = off[n + 1];
    if (D == 128) {
        const float2* Fp = (const float2*)F;
        float2 acc; acc.x = 0.f; acc.y = 0.f;
        int i = b;
        for (; i + 4 <= e; i += 4) {
            int s0 = csr[i], s1 = csr[i + 1], s2 = csr[i + 2], s3 = csr[i + 3];
            float2 v0 = Fp[(size_t)s0 * 64 + lane];
            float2 v1 = Fp[(size_t)s1 * 64 + lane];
            float2 v2 = Fp[(size_t)s2 * 64 + lane];
            float2 v3 = Fp[(size_t)s3 * 64 + lane];
            acc.x += (v0.x + v1.x) + (v2.x + v3.x);
            acc.y += (v0.y + v1.y) + (v2.y + v3.y);
        }
        for (; i < e; ++i) {
            int s = csr[i];
            float2 v = Fp[(size_t)s * 64 + lane];
            acc.x += v.x; acc.y += v.y;
        }
        ((float2*)OUT)[(size_t)n * 64 + lane] = acc;
    } else {
        float acc = 0.f;
        int i = b;
        for (; i + 4 <= e; i += 4) {
            int s0 = csr[i], s1 = csr[i + 1], s2 = csr[i + 2], s3 = csr[i + 3];
            float v0 = F[(size_t)s0 * 64 + lane];
            float v1 = F[(size_t)s1 * 64 + lane];
            float v2 = F[(size_t)s2 * 64 + lane];
            float v3 = F[(size_t)s3 * 64 + lane];
            acc += (v0 + v1) + (v2 + v3);
        }
        for (; i < e; ++i) acc += F[(size_t)csr[i] * 64 + lane];
        OUT[(size_t)n * 64 + lane] = acc;
    }
}

extern "C" void kernel_launch(void* const* d_in, const int* in_sizes, int n_in,
                              void* d_out, int out_size, void* d_ws, size_t ws_size,
                              hipStream_t stream) {
    const float* x   = (const float*)d_in[0];
    const int*   ei  = (const int*)d_in[1];
    const float* Wr1 = (const float*)d_in[2];
    const float* br1 = (const float*)d_in[3];
    const float* Wo1 = (const float*)d_in[4];
    const float* Wr2 = (const float*)d_in[5];
    const float* br2 = (const float*)d_in[6];
    const float* Wo2 = (const float*)d_in[7];
    float* out = (float*)d_out;

    const int N = in_sizes[0] / 128;  // 100000
    const int E = in_sizes[1] / 2;    // 1600000

    const int* srcv = ei;
    const int* dstv = ei + E;

    // workspace layout (keep deg/off/cursor 16B-aligned for int4 access)
    float* q1   = (float*)d_ws;                   // N*128   (later reused as h)
    float* agg1 = q1 + (size_t)N * 128;           // N*128   (later reused as p2)
    float* agg2 = agg1 + (size_t)N * 128;         // N*64
    int*   deg  = (int*)(agg2 + (size_t)N * 64);  // N        (N%4==0 -> aligned)
    int*   off  = deg + N;                        // N+1 (padded to N+8)
    int*   cur  = off + N + 8;                    // N
    int*   csr  = cur + N;                        // E
    int*   bsum = csr + E;                        // B
    int*   boff = bsum + 256;                     // B

    const int gemmBlocks = (N + BM - 1) / BM;
    const int aggBlocks = (N + 3) / 4;
    const int edgeBlocks = (E + 255) / 256;
    const int B = (N + 1023) / 1024;  // scan blocks (must be <= 256)
    const int fillBlocks = ((E + 1023) / 1024) * NPASS;

    // CSR build
    hipMemsetAsync(deg, 0, (size_t)N * sizeof(int), stream);
    hist_kernel<<<edgeBlocks, 256, 0, stream>>>(dstv, deg, E);
    scan1_kernel<<<B, 256, 0, stream>>>(deg, bsum, N);
    scan2_kernel<<<1, 256, 0, stream>>>(bsum, boff, off + N, B);
    scan3_kernel<<<B, 256, 0, stream>>>(deg, boff, off, cur, N);
    fill_kernel<<<fillBlocks, 256, 0, stream>>>(srcv, dstv, cur, csr, E, N);

    // layer 1: q1 = x @ Wr1^T ; agg1 = seg_sum(q1) ; h = relu(agg1 + b1 + x @ Wo1^T)
    gemm_k<128, 0><<<gemmBlocks, 256, 0, stream>>>(x, Wr1, nullptr, nullptr, q1, N);
    agg_k<128><<<aggBlocks, 256, 0, stream>>>(q1, csr, off, agg1, N);
    gemm_k<128, 1><<<gemmBlocks, 256, 0, stream>>>(x, Wo1, agg1, br1, q1 /*h*/, N);

    // layer 2: p2 = h @ Wr2^T ; agg2 = seg_sum(p2) ; out = agg2 + b2 + h @ Wo2^T
    gemm_k<64, 0><<<gemmBlocks, 256, 0, stream>>>(q1 /*h*/, Wr2, nullptr, nullptr, agg1 /*p2*/, N);
    agg_k<64><<<aggBlocks, 256, 0, stream>>>(agg1 /*p2*/, csr, off, agg2, N);
    gemm_k<64, 2><<<gemmBlocks, 256, 0, stream>>>(q1 /*h*/, Wo2, agg2, br2, out, N);
}

// Round 6
// 518.942 us; speedup vs baseline: 1.6306x; 1.1371x over previous
//
#include <hip/hip_runtime.h>
#include <hip/hip_bf16.h>

// GraphConv x2:
//   h   = relu( seg_sum(x[src]->dst) @ Wr1^T + b1 + x @ Wo1^T )
//   out =       seg_sum(h[src]->dst) @ Wr2^T + b2 + h @ Wo2^T
// seg_sum(h[src]) @ W^T == seg_sum((h @ W^T)[src]) -> transform first, aggregate after.
// CSR built in-kernel (partitioned hist + 3-kernel scan + partitioned fill).
// R2: parallel scan. R4: dst-range-partitioned fill (kills 16x write-allocate amp).
// R6: q1/p2 stored bf16 (gather traffic halved; agg was at 3.9TB/s fabric ceiling);
//     hist gets the same dst-range partition as fill.

#define BM 128
#define BK 32
#define NPASS 8

typedef unsigned short ushort_t;

__device__ __forceinline__ ushort_t f2bf(float f) {
    unsigned int u = __float_as_uint(f);
    unsigned int r = (u + 0x7fff + ((u >> 16) & 1)) >> 16;  // RTNE
    return (ushort_t)r;
}

__device__ __forceinline__ void bf2x(unsigned int v, float& lo, float& hi) {
    lo = __uint_as_float(v << 16);          // element at lower address
    hi = __uint_as_float(v & 0xffff0000u);  // element at higher address
}

// ---------------- CSR build ----------------

// R6: dst-range-partitioned histogram (same rationale as fill: per-XCD-L2-resident
// atomic targets, deg slice = 50KB; edge re-reads L3-served).
__global__ __launch_bounds__(256) void hist_kernel(const int* __restrict__ dst,
                                                   int* __restrict__ deg, int E, int N) {
    const int pass = blockIdx.x & (NPASS - 1);
    const int chunk = blockIdx.x >> 3;
    const int rangeSize = (N + NPASS - 1) / NPASS;
    const int lo = pass * rangeSize;
    const int hi = (lo + rangeSize < N) ? lo + rangeSize : N;
    const int base = chunk * 1024 + threadIdx.x * 4;
    if (base + 3 < E) {
        const int4 d4 = *(const int4*)(dst + base);
        if (d4.x >= lo && d4.x < hi) atomicAdd(&deg[d4.x], 1);
        if (d4.y >= lo && d4.y < hi) atomicAdd(&deg[d4.y], 1);
        if (d4.z >= lo && d4.z < hi) atomicAdd(&deg[d4.z], 1);
        if (d4.w >= lo && d4.w < hi) atomicAdd(&deg[d4.w], 1);
    } else {
        for (int i = 0; i < 4; ++i) {
            int e = base + i;
            if (e < E) {
                int d = dst[e];
                if (d >= lo && d < hi) atomicAdd(&deg[d], 1);
            }
        }
    }
}

// phase 1: per-block (1024-elem chunk) degree sums
__global__ __launch_bounds__(256) void scan1_kernel(const int* __restrict__ deg,
                                                    int* __restrict__ bsum, int N) {
    int t = threadIdx.x;
    int base = blockIdx.x * 1024 + t * 4;
    int s = 0;
    if (base + 3 < N) {
        int4 v = *(const int4*)(deg + base);
        s = v.x + v.y + v.z + v.w;
    } else {
#pragma unroll
        for (int i = 0; i < 4; ++i)
            if (base + i < N) s += deg[base + i];
    }
#pragma unroll
    for (int d = 32; d > 0; d >>= 1) s += __shfl_down(s, d);
    __shared__ int wsum[4];
    int lane = t & 63, w = t >> 6;
    if (lane == 0) wsum[w] = s;
    __syncthreads();
    if (t == 0) bsum[blockIdx.x] = wsum[0] + wsum[1] + wsum[2] + wsum[3];
}

// phase 2: scan block sums (B <= 256), write exclusive block offsets + off[N]
__global__ __launch_bounds__(256) void scan2_kernel(const int* __restrict__ bsum,
                                                    int* __restrict__ boff,
                                                    int* __restrict__ offN, int B) {
    __shared__ int s[256];
    int t = threadIdx.x;
    int v = (t < B) ? bsum[t] : 0;
    s[t] = v;
    __syncthreads();
    for (int d = 1; d < 256; d <<= 1) {
        int u = (t >= d) ? s[t - d] : 0;
        __syncthreads();
        s[t] += u;
        __syncthreads();
    }
    if (t < B) boff[t] = s[t] - v;   // exclusive
    if (t == B - 1) *offN = s[t];    // total
}

// phase 3: per-block local exclusive scan + block offset -> off, cursor
__global__ __launch_bounds__(256) void scan3_kernel(const int* __restrict__ deg,
                                                    const int* __restrict__ boff,
                                                    int* __restrict__ off,
                                                    int* __restrict__ cursor, int N) {
    int t = threadIdx.x;
    int base = blockIdx.x * 1024 + t * 4;
    int d0 = 0, d1 = 0, d2 = 0, d3 = 0;
    if (base + 3 < N) {
        int4 v = *(const int4*)(deg + base);
        d0 = v.x; d1 = v.y; d2 = v.z; d3 = v.w;
    } else {
        if (base + 0 < N) d0 = deg[base + 0];
        if (base + 1 < N) d1 = deg[base + 1];
        if (base + 2 < N) d2 = deg[base + 2];
    }
    int s = d0 + d1 + d2 + d3;
    int lane = t & 63, w = t >> 6;
    int incl = s;
#pragma unroll
    for (int d = 1; d < 64; d <<= 1) {
        int u = __shfl_up(incl, d);
        if (lane >= d) incl += u;
    }
    __shared__ int wsum[4];
    if (lane == 63) wsum[w] = incl;
    __syncthreads();
    int wpre = 0;
#pragma unroll
    for (int i = 0; i < 3; ++i)
        if (i < w) wpre += wsum[i];
    int excl = incl - s + wpre + boff[blockIdx.x];
    int e0 = excl, e1 = e0 + d0, e2 = e1 + d1, e3 = e2 + d2;
    if (base + 3 < N) {
        *(int4*)(off + base) = make_int4(e0, e1, e2, e3);
        *(int4*)(cursor + base) = make_int4(e0, e1, e2, e3);
    } else {
        if (base + 0 < N) { off[base + 0] = e0; cursor[base + 0] = e0; }
        if (base + 1 < N) { off[base + 1] = e1; cursor[base + 1] = e1; }
        if (base + 2 < N) { off[base + 2] = e2; cursor[base + 2] = e2; }
    }
}

// R4: dst-range-partitioned fill.
__global__ __launch_bounds__(256) void fill_kernel(const int* __restrict__ src,
                                                   const int* __restrict__ dst,
                                                   int* __restrict__ cursor,
                                                   int* __restrict__ csr, int E, int N) {
    const int pass = blockIdx.x & (NPASS - 1);
    const int chunk = blockIdx.x >> 3;
    const int rangeSize = (N + NPASS - 1) / NPASS;
    const int lo = pass * rangeSize;
    const int hi = (lo + rangeSize < N) ? lo + rangeSize : N;
    const int base = chunk * 1024 + threadIdx.x * 4;
    if (base + 3 < E) {
        const int4 s4 = *(const int4*)(src + base);
        const int4 d4 = *(const int4*)(dst + base);
        if (d4.x >= lo && d4.x < hi) csr[atomicAdd(&cursor[d4.x], 1)] = s4.x;
        if (d4.y >= lo && d4.y < hi) csr[atomicAdd(&cursor[d4.y], 1)] = s4.y;
        if (d4.z >= lo && d4.z < hi) csr[atomicAdd(&cursor[d4.z], 1)] = s4.z;
        if (d4.w >= lo && d4.w < hi) csr[atomicAdd(&cursor[d4.w], 1)] = s4.w;
    } else {
        for (int i = 0; i < 4; ++i) {
            int e = base + i;
            if (e < E) {
                int d = dst[e];
                if (d >= lo && d < hi) csr[atomicAdd(&cursor[d], 1)] = src[e];
            }
        }
    }
}

// ---------------- GEMM: OUT[g][j] = sum_k X[g][k] * W[j][k] (+ epilogue) ----------------
// X: [Nrows][128] fp32 row-major. W: [BN][128] fp32 row-major.
// EPI: 0 none, 1 relu(AGG+bias+acc), 2 AGG+bias+acc.  OB: 1 -> write bf16, 0 -> fp32.

template <int BN, int EPI, int OB>
__global__ __launch_bounds__(256, 4)
void gemm_k(const float* __restrict__ X, const float* __restrict__ W,
            const float* __restrict__ AGG, const float* __restrict__ bias,
            void* __restrict__ OUTv, int Nrows) {
    __shared__ float xs[BK][BM + 4];   // transposed x chunk: xs[k][row]
    __shared__ float wsh[BK][BN + 4];  // transposed W chunk: wsh[k][col]

    const int tid = threadIdx.x;
    const int tc = tid & 15;   // col group
    const int tr = tid >> 4;   // row group (0..15)
    const int rowBase = blockIdx.x * BM;
    constexpr int CG = BN / 64;  // 2 for BN=128, 1 for BN=64

    float acc[8][4 * CG];
#pragma unroll
    for (int i = 0; i < 8; ++i)
#pragma unroll
        for (int j = 0; j < 4 * CG; ++j) acc[i][j] = 0.f;

    const int srow = tid >> 3;       // 0..31
    const int skq = (tid & 7) * 4;   // k offset within chunk: 0,4,..,28

    for (int kc = 0; kc < 128; kc += BK) {
#pragma unroll
        for (int i = 0; i < 4; ++i) {
            int r = srow + i * 32;
            int g = rowBase + r;
            g = g < Nrows ? g : Nrows - 1;
            const float4 v = *(const float4*)(X + (size_t)g * 128 + kc + skq);
            xs[skq + 0][r] = v.x;
            xs[skq + 1][r] = v.y;
            xs[skq + 2][r] = v.z;
            xs[skq + 3][r] = v.w;
        }
#pragma unroll
        for (int i = 0; i < BN / 32; ++i) {
            int j = srow + i * 32;
            const float4 v = *(const float4*)(W + (size_t)j * 128 + kc + skq);
            wsh[skq + 0][j] = v.x;
            wsh[skq + 1][j] = v.y;
            wsh[skq + 2][j] = v.z;
            wsh[skq + 3][j] = v.w;
        }
        __syncthreads();
#pragma unroll
        for (int k = 0; k < BK; ++k) {
            const float4 xa = *(const float4*)&xs[k][tr * 8];
            const float4 xb = *(const float4*)&xs[k][tr * 8 + 4];
            float xr[8] = {xa.x, xa.y, xa.z, xa.w, xb.x, xb.y, xb.z, xb.w};
            float wv[4 * CG];
            const float4 wa = *(const float4*)&wsh[k][tc * 4];
            wv[0] = wa.x; wv[1] = wa.y; wv[2] = wa.z; wv[3] = wa.w;
            if (CG == 2) {
                const float4 wb = *(const float4*)&wsh[k][64 + tc * 4];
                wv[4] = wb.x; wv[5] = wb.y; wv[6] = wb.z; wv[7] = wb.w;
            }
#pragma unroll
            for (int i = 0; i < 8; ++i)
#pragma unroll
                for (int j = 0; j < 4 * CG; ++j) acc[i][j] += xr[i] * wv[j];
        }
        __syncthreads();
    }

    // epilogue
#pragma unroll
    for (int i = 0; i < 8; ++i) {
        int g = rowBase + tr * 8 + i;
        if (g >= Nrows) continue;
#pragma unroll
        for (int cg = 0; cg < CG; ++cg) {
            int c = cg * 64 + tc * 4;
            float4 r;
            r.x = acc[i][cg * 4 + 0];
            r.y = acc[i][cg * 4 + 1];
            r.z = acc[i][cg * 4 + 2];
            r.w = acc[i][cg * 4 + 3];
            if (EPI != 0) {
                const float4 a = *(const float4*)(AGG + (size_t)g * BN + c);
                const float4 bb = *(const float4*)(bias + c);
                r.x += a.x + bb.x;
                r.y += a.y + bb.y;
                r.z += a.z + bb.z;
                r.w += a.w + bb.w;
                if (EPI == 1) {
                    r.x = r.x > 0.f ? r.x : 0.f;
                    r.y = r.y > 0.f ? r.y : 0.f;
                    r.z = r.z > 0.f ? r.z : 0.f;
                    r.w = r.w > 0.f ? r.w : 0.f;
                }
            }
            if (OB) {
                ushort_t* OUT = (ushort_t*)OUTv;
                ushort4 o;
                o.x = f2bf(r.x); o.y = f2bf(r.y); o.z = f2bf(r.z); o.w = f2bf(r.w);
                *(ushort4*)(OUT + (size_t)g * BN + c) = o;
            } else {
                float* OUT = (float*)OUTv;
                *(float4*)(OUT + (size_t)g * BN + c) = r;
            }
        }
    }
}

// ---------------- CSR gather-aggregate (bf16 in, fp32 out) ----------------
// D=128: 64 lanes/node, 2 bf16 cols/lane. D=64: 32 lanes/node, 2 bf16 cols/lane.

template <int D>
__global__ __launch_bounds__(256)
void agg_k(const ushort_t* __restrict__ F, const int* __restrict__ csr,
           const int* __restrict__ off, float* __restrict__ OUT, int N) {
    constexpr int LPN = (D == 128) ? 64 : 32;  // lanes per node
    constexpr int NPB = 256 / LPN;             // nodes per block
    int n = blockIdx.x * NPB + (threadIdx.x / LPN);
    if (n >= N) return;
    int lane = threadIdx.x & (LPN - 1);
    int b = off[n], e = off[n + 1];
    const size_t col = (size_t)lane * 2;
    float a0 = 0.f, a1 = 0.f;
    int i = b;
    for (; i + 4 <= e; i += 4) {
        int s0 = csr[i], s1 = csr[i + 1], s2 = csr[i + 2], s3 = csr[i + 3];
        unsigned int v0 = *(const unsigned int*)(F + (size_t)s0 * D + col);
        unsigned int v1 = *(const unsigned int*)(F + (size_t)s1 * D + col);
        unsigned int v2 = *(const unsigned int*)(F + (size_t)s2 * D + col);
        unsigned int v3 = *(const unsigned int*)(F + (size_t)s3 * D + col);
        float l0, h0, l1, h1, l2, h2, l3, h3;
        bf2x(v0, l0, h0); bf2x(v1, l1, h1); bf2x(v2, l2, h2); bf2x(v3, l3, h3);
        a0 += (l0 + l1) + (l2 + l3);
        a1 += (h0 + h1) + (h2 + h3);
    }
    for (; i < e; ++i) {
        unsigned int v = *(const unsigned int*)(F + (size_t)csr[i] * D + col);
        float l, h;
        bf2x(v, l, h);
        a0 += l; a1 += h;
    }
    float2 r; r.x = a0; r.y = a1;
    *(float2*)(OUT + (size_t)n * D + col) = r;
}

extern "C" void kernel_launch(void* const* d_in, const int* in_sizes, int n_in,
                              void* d_out, int out_size, void* d_ws, size_t ws_size,
                              hipStream_t stream) {
    const float* x   = (const float*)d_in[0];
    const int*   ei  = (const int*)d_in[1];
    const float* Wr1 = (const float*)d_in[2];
    const float* br1 = (const float*)d_in[3];
    const float* Wo1 = (const float*)d_in[4];
    const float* Wr2 = (const float*)d_in[5];
    const float* br2 = (const float*)d_in[6];
    const float* Wo2 = (const float*)d_in[7];
    float* out = (float*)d_out;

    const int N = in_sizes[0] / 128;  // 100000
    const int E = in_sizes[1] / 2;    // 1600000

    const int* srcv = ei;
    const int* dstv = ei + E;

    // workspace layout (16B-aligned sections; all float sections first)
    float*    h    = (float*)d_ws;                    // N*128 fp32
    float*    agg1 = h + (size_t)N * 128;             // N*128 fp32
    float*    agg2 = agg1 + (size_t)N * 128;          // N*64  fp32
    ushort_t* qb   = (ushort_t*)(agg2 + (size_t)N * 64);  // N*128 bf16 (reused as p2b N*64)
    int*      deg  = (int*)(qb + (size_t)N * 128);    // N
    int*      off  = deg + N;                         // N+1 (padded to N+8)
    int*      cur  = off + N + 8;                     // N
    int*      csr  = cur + N;                         // E
    int*      bsum = csr + E;                         // <=256
    int*      boff = bsum + 256;                      // <=256

    const int gemmBlocks = (N + BM - 1) / BM;
    const int agg128Blocks = (N + 3) / 4;
    const int agg64Blocks = (N + 7) / 8;
    const int B = (N + 1023) / 1024;  // scan blocks (must be <= 256)
    const int edgePassBlocks = ((E + 1023) / 1024) * NPASS;

    // CSR build
    hipMemsetAsync(deg, 0, (size_t)N * sizeof(int), stream);
    hist_kernel<<<edgePassBlocks, 256, 0, stream>>>(dstv, deg, E, N);
    scan1_kernel<<<B, 256, 0, stream>>>(deg, bsum, N);
    scan2_kernel<<<1, 256, 0, stream>>>(bsum, boff, off + N, B);
    scan3_kernel<<<B, 256, 0, stream>>>(deg, boff, off, cur, N);
    fill_kernel<<<edgePassBlocks, 256, 0, stream>>>(srcv, dstv, cur, csr, E, N);

    // layer 1: qb = bf16(x @ Wr1^T) ; agg1 = seg_sum(qb) ; h = relu(agg1 + b1 + x @ Wo1^T)
    gemm_k<128, 0, 1><<<gemmBlocks, 256, 0, stream>>>(x, Wr1, nullptr, nullptr, qb, N);
    agg_k<128><<<agg128Blocks, 256, 0, stream>>>(qb, csr, off, agg1, N);
    gemm_k<128, 1, 0><<<gemmBlocks, 256, 0, stream>>>(x, Wo1, agg1, br1, h, N);

    // layer 2: p2b = bf16(h @ Wr2^T) ; agg2 = seg_sum(p2b) ; out = agg2 + b2 + h @ Wo2^T
    gemm_k<64, 0, 1><<<gemmBlocks, 256, 0, stream>>>(h, Wr2, nullptr, nullptr, qb /*p2b*/, N);
    agg_k<64><<<agg64Blocks, 256, 0, stream>>>(qb /*p2b*/, csr, off, agg2, N);
    gemm_k<64, 2, 0><<<gemmBlocks, 256, 0, stream>>>(h, Wo2, agg2, br2, out, N);
}

// Round 8
// 493.485 us; speedup vs baseline: 1.7148x; 1.0516x over previous
//
#include <hip/hip_runtime.h>
#include <hip/hip_bf16.h>

// GraphConv x2:
//   h   = relu( seg_sum(x[src]->dst) @ Wr1^T + b1 + x @ Wo1^T )
//   out =       seg_sum(h[src]->dst) @ Wr2^T + b2 + h @ Wo2^T
// seg_sum(h[src]) @ W^T == seg_sum((h @ W^T)[src]) -> transform first, aggregate after.
// CSR built in-kernel (partitioned hist + 3-kernel scan + partitioned fill).
// R2: parallel scan. R4: dst-range-partitioned fill (kills 16x write-allocate amp).
// R6: q1/p2 bf16 (agg gather halved); partitioned hist.
// R7: gemm __launch_bounds__(256,2) — R6 profile showed VGPR=64 (forced spills:
//     +37MB scratch WRITE on gemm); agg: 32-lane/node uint2 loads (was issue-bound
//     at 3.3TB/s with 4B/lane); agg outputs bf16 (halve agg writes + gemm AGG reads).

#define BM 128
#define BK 32
#define NPASS 8

typedef unsigned short ushort_t;

__device__ __forceinline__ ushort_t f2bf(float f) {
    unsigned int u = __float_as_uint(f);
    unsigned int r = (u + 0x7fff + ((u >> 16) & 1)) >> 16;  // RTNE
    return (ushort_t)r;
}

__device__ __forceinline__ float bf2f(ushort_t v) {
    return __uint_as_float(((unsigned int)v) << 16);
}

__device__ __forceinline__ void bf2x(unsigned int v, float& lo, float& hi) {
    lo = __uint_as_float(v << 16);          // element at lower address
    hi = __uint_as_float(v & 0xffff0000u);  // element at higher address
}

// ---------------- CSR build ----------------

// dst-range-partitioned histogram (pass p <-> XCD p under round-robin block->XCD:
// per-XCD-L2-resident atomic targets; edge re-reads L3-served).
__global__ __launch_bounds__(256) void hist_kernel(const int* __restrict__ dst,
                                                   int* __restrict__ deg, int E, int N) {
    const int pass = blockIdx.x & (NPASS - 1);
    const int chunk = blockIdx.x >> 3;
    const int rangeSize = (N + NPASS - 1) / NPASS;
    const int lo = pass * rangeSize;
    const int hi = (lo + rangeSize < N) ? lo + rangeSize : N;
    const int base = chunk * 1024 + threadIdx.x * 4;
    if (base + 3 < E) {
        const int4 d4 = *(const int4*)(dst + base);
        if (d4.x >= lo && d4.x < hi) atomicAdd(&deg[d4.x], 1);
        if (d4.y >= lo && d4.y < hi) atomicAdd(&deg[d4.y], 1);
        if (d4.z >= lo && d4.z < hi) atomicAdd(&deg[d4.z], 1);
        if (d4.w >= lo && d4.w < hi) atomicAdd(&deg[d4.w], 1);
    } else {
        for (int i = 0; i < 4; ++i) {
            int e = base + i;
            if (e < E) {
                int d = dst[e];
                if (d >= lo && d < hi) atomicAdd(&deg[d], 1);
            }
        }
    }
}

// phase 1: per-block (1024-elem chunk) degree sums
__global__ __launch_bounds__(256) void scan1_kernel(const int* __restrict__ deg,
                                                    int* __restrict__ bsum, int N) {
    int t = threadIdx.x;
    int base = blockIdx.x * 1024 + t * 4;
    int s = 0;
    if (base + 3 < N) {
        int4 v = *(const int4*)(deg + base);
        s = v.x + v.y + v.z + v.w;
    } else {
#pragma unroll
        for (int i = 0; i < 4; ++i)
            if (base + i < N) s += deg[base + i];
    }
#pragma unroll
    for (int d = 32; d > 0; d >>= 1) s += __shfl_down(s, d);
    __shared__ int wsum[4];
    int lane = t & 63, w = t >> 6;
    if (lane == 0) wsum[w] = s;
    __syncthreads();
    if (t == 0) bsum[blockIdx.x] = wsum[0] + wsum[1] + wsum[2] + wsum[3];
}

// phase 2: scan block sums (B <= 256), write exclusive block offsets + off[N]
__global__ __launch_bounds__(256) void scan2_kernel(const int* __restrict__ bsum,
                                                    int* __restrict__ boff,
                                                    int* __restrict__ offN, int B) {
    __shared__ int s[256];
    int t = threadIdx.x;
    int v = (t < B) ? bsum[t] : 0;
    s[t] = v;
    __syncthreads();
    for (int d = 1; d < 256; d <<= 1) {
        int u = (t >= d) ? s[t - d] : 0;
        __syncthreads();
        s[t] += u;
        __syncthreads();
    }
    if (t < B) boff[t] = s[t] - v;   // exclusive
    if (t == B - 1) *offN = s[t];    // total
}

// phase 3: per-block local exclusive scan + block offset -> off, cursor
__global__ __launch_bounds__(256) void scan3_kernel(const int* __restrict__ deg,
                                                    const int* __restrict__ boff,
                                                    int* __restrict__ off,
                                                    int* __restrict__ cursor, int N) {
    int t = threadIdx.x;
    int base = blockIdx.x * 1024 + t * 4;
    int d0 = 0, d1 = 0, d2 = 0, d3 = 0;
    if (base + 3 < N) {
        int4 v = *(const int4*)(deg + base);
        d0 = v.x; d1 = v.y; d2 = v.z; d3 = v.w;
    } else {
        if (base + 0 < N) d0 = deg[base + 0];
        if (base + 1 < N) d1 = deg[base + 1];
        if (base + 2 < N) d2 = deg[base + 2];
    }
    int s = d0 + d1 + d2 + d3;
    int lane = t & 63, w = t >> 6;
    int incl = s;
#pragma unroll
    for (int d = 1; d < 64; d <<= 1) {
        int u = __shfl_up(incl, d);
        if (lane >= d) incl += u;
    }
    __shared__ int wsum[4];
    if (lane == 63) wsum[w] = incl;
    __syncthreads();
    int wpre = 0;
#pragma unroll
    for (int i = 0; i < 3; ++i)
        if (i < w) wpre += wsum[i];
    int excl = incl - s + wpre + boff[blockIdx.x];
    int e0 = excl, e1 = e0 + d0, e2 = e1 + d1, e3 = e2 + d2;
    if (base + 3 < N) {
        *(int4*)(off + base) = make_int4(e0, e1, e2, e3);
        *(int4*)(cursor + base) = make_int4(e0, e1, e2, e3);
    } else {
        if (base + 0 < N) { off[base + 0] = e0; cursor[base + 0] = e0; }
        if (base + 1 < N) { off[base + 1] = e1; cursor[base + 1] = e1; }
        if (base + 2 < N) { off[base + 2] = e2; cursor[base + 2] = e2; }
    }
}

// dst-range-partitioned fill.
__global__ __launch_bounds__(256) void fill_kernel(const int* __restrict__ src,
                                                   const int* __restrict__ dst,
                                                   int* __restrict__ cursor,
                                                   int* __restrict__ csr, int E, int N) {
    const int pass = blockIdx.x & (NPASS - 1);
    const int chunk = blockIdx.x >> 3;
    const int rangeSize = (N + NPASS - 1) / NPASS;
    const int lo = pass * rangeSize;
    const int hi = (lo + rangeSize < N) ? lo + rangeSize : N;
    const int base = chunk * 1024 + threadIdx.x * 4;
    if (base + 3 < E) {
        const int4 s4 = *(const int4*)(src + base);
        const int4 d4 = *(const int4*)(dst + base);
        if (d4.x >= lo && d4.x < hi) csr[atomicAdd(&cursor[d4.x], 1)] = s4.x;
        if (d4.y >= lo && d4.y < hi) csr[atomicAdd(&cursor[d4.y], 1)] = s4.y;
        if (d4.z >= lo && d4.z < hi) csr[atomicAdd(&cursor[d4.z], 1)] = s4.z;
        if (d4.w >= lo && d4.w < hi) csr[atomicAdd(&cursor[d4.w], 1)] = s4.w;
    } else {
        for (int i = 0; i < 4; ++i) {
            int e = base + i;
            if (e < E) {
                int d = dst[e];
                if (d >= lo && d < hi) csr[atomicAdd(&cursor[d], 1)] = src[e];
            }
        }
    }
}

// ---------------- GEMM: OUT[g][j] = sum_k X[g][k] * W[j][k] (+ epilogue) ----------------
// X: [Nrows][128] fp32. W: [BN][128] fp32. EPI: 0 none, 1 relu(AGG+bias+acc), 2 AGG+bias+acc.
// OB: 1 -> OUT bf16, 0 -> fp32. AB: 1 -> AGG bf16, 0 -> fp32.
// launch_bounds(256,2): LDS caps at 4 blocks/CU anyway; (256,4) made the compiler
// clamp to 64 VGPR and spill (R6 profile: VGPR=64, +37MB scratch writes).

template <int BN, int EPI, int OB, int AB>
__global__ __launch_bounds__(256, 2)
void gemm_k(const float* __restrict__ X, const float* __restrict__ W,
            const void* __restrict__ AGGv, const float* __restrict__ bias,
            void* __restrict__ OUTv, int Nrows) {
    __shared__ float xs[BK][BM + 4];   // transposed x chunk: xs[k][row]
    __shared__ float wsh[BK][BN + 4];  // transposed W chunk: wsh[k][col]

    const int tid = threadIdx.x;
    const int tc = tid & 15;   // col group
    const int tr = tid >> 4;   // row group (0..15)
    const int rowBase = blockIdx.x * BM;
    constexpr int CG = BN / 64;  // 2 for BN=128, 1 for BN=64

    float acc[8][4 * CG];
#pragma unroll
    for (int i = 0; i < 8; ++i)
#pragma unroll
        for (int j = 0; j < 4 * CG; ++j) acc[i][j] = 0.f;

    const int srow = tid >> 3;       // 0..31
    const int skq = (tid & 7) * 4;   // k offset within chunk: 0,4,..,28

    for (int kc = 0; kc < 128; kc += BK) {
#pragma unroll
        for (int i = 0; i < 4; ++i) {
            int r = srow + i * 32;
            int g = rowBase + r;
            g = g < Nrows ? g : Nrows - 1;
            const float4 v = *(const float4*)(X + (size_t)g * 128 + kc + skq);
            xs[skq + 0][r] = v.x;
            xs[skq + 1][r] = v.y;
            xs[skq + 2][r] = v.z;
            xs[skq + 3][r] = v.w;
        }
#pragma unroll
        for (int i = 0; i < BN / 32; ++i) {
            int j = srow + i * 32;
            const float4 v = *(const float4*)(W + (size_t)j * 128 + kc + skq);
            wsh[skq + 0][j] = v.x;
            wsh[skq + 1][j] = v.y;
            wsh[skq + 2][j] = v.z;
            wsh[skq + 3][j] = v.w;
        }
        __syncthreads();
#pragma unroll
        for (int k = 0; k < BK; ++k) {
            const float4 xa = *(const float4*)&xs[k][tr * 8];
            const float4 xb = *(const float4*)&xs[k][tr * 8 + 4];
            float xr[8] = {xa.x, xa.y, xa.z, xa.w, xb.x, xb.y, xb.z, xb.w};
            float wv[4 * CG];
            const float4 wa = *(const float4*)&wsh[k][tc * 4];
            wv[0] = wa.x; wv[1] = wa.y; wv[2] = wa.z; wv[3] = wa.w;
            if (CG == 2) {
                const float4 wb = *(const float4*)&wsh[k][64 + tc * 4];
                wv[4] = wb.x; wv[5] = wb.y; wv[6] = wb.z; wv[7] = wb.w;
            }
#pragma unroll
            for (int i = 0; i < 8; ++i)
#pragma unroll
                for (int j = 0; j < 4 * CG; ++j) acc[i][j] += xr[i] * wv[j];
        }
        __syncthreads();
    }

    // epilogue
#pragma unroll
    for (int i = 0; i < 8; ++i) {
        int g = rowBase + tr * 8 + i;
        if (g >= Nrows) continue;
#pragma unroll
        for (int cg = 0; cg < CG; ++cg) {
            int c = cg * 64 + tc * 4;
            float4 r;
            r.x = acc[i][cg * 4 + 0];
            r.y = acc[i][cg * 4 + 1];
            r.z = acc[i][cg * 4 + 2];
            r.w = acc[i][cg * 4 + 3];
            if (EPI != 0) {
                float ax, ay, az, aw;
                if (AB) {
                    const ushort_t* A = (const ushort_t*)AGGv;
                    ushort4 a4 = *(const ushort4*)(A + (size_t)g * BN + c);
                    ax = bf2f(a4.x); ay = bf2f(a4.y); az = bf2f(a4.z); aw = bf2f(a4.w);
                } else {
                    const float4 a = *(const float4*)((const float*)AGGv + (size_t)g * BN + c);
                    ax = a.x; ay = a.y; az = a.z; aw = a.w;
                }
                const float4 bb = *(const float4*)(bias + c);
                r.x += ax + bb.x;
                r.y += ay + bb.y;
                r.z += az + bb.z;
                r.w += aw + bb.w;
                if (EPI == 1) {
                    r.x = r.x > 0.f ? r.x : 0.f;
                    r.y = r.y > 0.f ? r.y : 0.f;
                    r.z = r.z > 0.f ? r.z : 0.f;
                    r.w = r.w > 0.f ? r.w : 0.f;
                }
            }
            if (OB) {
                ushort_t* OUT = (ushort_t*)OUTv;
                ushort4 o;
                o.x = f2bf(r.x); o.y = f2bf(r.y); o.z = f2bf(r.z); o.w = f2bf(r.w);
                *(ushort4*)(OUT + (size_t)g * BN + c) = o;
            } else {
                float* OUT = (float*)OUTv;
                *(float4*)(OUT + (size_t)g * BN + c) = r;
            }
        }
    }
}

// ---------------- CSR gather-aggregate (bf16 in, bf16/fp32 out) ----------------
// R7: uint2 (4 bf16) per lane: D=128 -> 32 lanes/node, D=64 -> 16 lanes/node.
// Halves load-instruction count vs R6 (was issue-bound at 3.3TB/s).

template <int D, int OB>
__global__ __launch_bounds__(256)
void agg_k(const ushort_t* __restrict__ F, const int* __restrict__ csr,
           const int* __restrict__ off, void* __restrict__ OUTv, int N) {
    constexpr int LPN = (D == 128) ? 32 : 16;  // lanes per node
    constexpr int NPB = 256 / LPN;             // nodes per block
    int n = blockIdx.x * NPB + (threadIdx.x / LPN);
    if (n >= N) return;
    int lane = threadIdx.x & (LPN - 1);
    int b = off[n], e = off[n + 1];
    const size_t col = (size_t)lane * 4;
    float a0 = 0.f, a1 = 0.f, a2 = 0.f, a3 = 0.f;
    int i = b;
    for (; i + 4 <= e; i += 4) {
        int s0 = csr[i], s1 = csr[i + 1], s2 = csr[i + 2], s3 = csr[i + 3];
        uint2 v0 = *(const uint2*)(F + (size_t)s0 * D + col);
        uint2 v1 = *(const uint2*)(F + (size_t)s1 * D + col);
        uint2 v2 = *(const uint2*)(F + (size_t)s2 * D + col);
        uint2 v3 = *(const uint2*)(F + (size_t)s3 * D + col);
        float l, h;
        bf2x(v0.x, l, h); a0 += l; a1 += h;
        bf2x(v0.y, l, h); a2 += l; a3 += h;
        bf2x(v1.x, l, h); a0 += l; a1 += h;
        bf2x(v1.y, l, h); a2 += l; a3 += h;
        bf2x(v2.x, l, h); a0 += l; a1 += h;
        bf2x(v2.y, l, h); a2 += l; a3 += h;
        bf2x(v3.x, l, h); a0 += l; a1 += h;
        bf2x(v3.y, l, h); a2 += l; a3 += h;
    }
    for (; i < e; ++i) {
        uint2 v = *(const uint2*)(F + (size_t)csr[i] * D + col);
        float l, h;
        bf2x(v.x, l, h); a0 += l; a1 += h;
        bf2x(v.y, l, h); a2 += l; a3 += h;
    }
    if (OB) {
        ushort_t* OUT = (ushort_t*)OUTv;
        ushort4 o;
        o.x = f2bf(a0); o.y = f2bf(a1); o.z = f2bf(a2); o.w = f2bf(a3);
        *(ushort4*)(OUT + (size_t)n * D + col) = o;
    } else {
        float* OUT = (float*)OUTv;
        float4 r; r.x = a0; r.y = a1; r.z = a2; r.w = a3;
        *(float4*)(OUT + (size_t)n * D + col) = r;
    }
}

extern "C" void kernel_launch(void* const* d_in, const int* in_sizes, int n_in,
                              void* d_out, int out_size, void* d_ws, size_t ws_size,
                              hipStream_t stream) {
    const float* x   = (const float*)d_in[0];
    const int*   ei  = (const int*)d_in[1];
    const float* Wr1 = (const float*)d_in[2];
    const float* br1 = (const float*)d_in[3];
    const float* Wo1 = (const float*)d_in[4];
    const float* Wr2 = (const float*)d_in[5];
    const float* br2 = (const float*)d_in[6];
    const float* Wo2 = (const float*)d_in[7];
    float* out = (float*)d_out;

    const int N = in_sizes[0] / 128;  // 100000
    const int E = in_sizes[1] / 2;    // 1600000

    const int* srcv = ei;
    const int* dstv = ei + E;

    // workspace layout (16B-aligned sections)
    float*    h    = (float*)d_ws;                      // N*128 fp32
    ushort_t* qb   = (ushort_t*)(h + (size_t)N * 128);  // N*128 bf16 (reused as p2b N*64)
    ushort_t* a1b  = qb + (size_t)N * 128;              // N*128 bf16
    ushort_t* a2b  = a1b + (size_t)N * 128;             // N*64  bf16
    int*      deg  = (int*)(a2b + (size_t)N * 64);      // N
    int*      off  = deg + N;                           // N+1 (padded to N+8)
    int*      cur  = off + N + 8;                       // N
    int*      csr  = cur + N;                           // E
    int*      bsum = csr + E;                           // <=256
    int*      boff = bsum + 256;                        // <=256

    const int gemmBlocks = (N + BM - 1) / BM;
    const int agg128Blocks = (N + 7) / 8;
    const int agg64Blocks = (N + 15) / 16;
    const int B = (N + 1023) / 1024;  // scan blocks (must be <= 256)
    const int edgePassBlocks = ((E + 1023) / 1024) * NPASS;

    // CSR build
    hipMemsetAsync(deg, 0, (size_t)N * sizeof(int), stream);
    hist_kernel<<<edgePassBlocks, 256, 0, stream>>>(dstv, deg, E, N);
    scan1_kernel<<<B, 256, 0, stream>>>(deg, bsum, N);
    scan2_kernel<<<1, 256, 0, stream>>>(bsum, boff, off + N, B);
    scan3_kernel<<<B, 256, 0, stream>>>(deg, boff, off, cur, N);
    fill_kernel<<<edgePassBlocks, 256, 0, stream>>>(srcv, dstv, cur, csr, E, N);

    // layer 1: qb = bf16(x @ Wr1^T) ; a1b = bf16(seg_sum(qb)) ; h = relu(a1b + b1 + x @ Wo1^T)
    gemm_k<128, 0, 1, 0><<<gemmBlocks, 256, 0, stream>>>(x, Wr1, nullptr, nullptr, qb, N);
    agg_k<128, 1><<<agg128Blocks, 256, 0, stream>>>(qb, csr, off, a1b, N);
    gemm_k<128, 1, 0, 1><<<gemmBlocks, 256, 0, stream>>>(x, Wo1, a1b, br1, h, N);

    // layer 2: p2b = bf16(h @ Wr2^T) ; a2b = bf16(seg_sum(p2b)) ; out = a2b + b2 + h @ Wo2^T
    gemm_k<64, 0, 1, 0><<<gemmBlocks, 256, 0, stream>>>(h, Wr2, nullptr, nullptr, qb /*p2b*/, N);
    agg_k<64, 1><<<agg64Blocks, 256, 0, stream>>>(qb /*p2b*/, csr, off, a2b, N);
    gemm_k<64, 2, 0, 1><<<gemmBlocks, 256, 0, stream>>>(h, Wo2, a2b, br2, out, N);
}